// Round 4
// baseline (973.362 us; speedup 1.0000x reference)
//
#include <hip/hip_runtime.h>
#include <hip/hip_cooperative_groups.h>

namespace cg = cooperative_groups;

#define N_NODES 10000
#define ROW4    2500          // float4 per adj row
#define CAP     64            // max nnz stored/row (Binomial(10000,0.002) tail past 64 ~1e-15)
#define GEMM_CHUNKS 1250      // phase A: 8 rows each (x@W gemms)
#define SPAR_CHUNKS 2500      // phase A: 4 rows each (sparsify)
#define TOTAL_A     (GEMM_CHUNKS + SPAR_CHUNKS)
#define ROW_CHUNKS  1250      // phases B..D: 8 rows each
#define MAX_GRID    1024

// ---- workspace layout (float-element offsets) ----
#define OFF_CNT     0                         // int[10000]
#define OFF_COLSUM  10000                     // float[64]
#define OFF_SSRC    10064                     // float[10000]
#define OFF_SDST    20064                     // float[10000]
#define OFF_PAIRS   30064                     // float2[10000*64]  (8B-aligned: 30064*4 % 8 == 0)
#define OFF_B1      1310064                   // float[10000*64]
#define OFF_B2      1950064
#define OFF_B3      2590064
#define OFF_B4      3230064
// total 3,870,064 floats = 15.5 MB

__device__ __forceinline__ float wave_sum(float v) {
    #pragma unroll
    for (int off = 32; off >= 1; off >>= 1) v += __shfl_xor(v, off, 64);
    return v;
}
__device__ __forceinline__ float wave_max(float v) {
    #pragma unroll
    for (int off = 32; off >= 1; off >>= 1) v = fmaxf(v, __shfl_xor(v, off, 64));
    return v;
}

struct KArgs {
    const float4* adj4; const float* x; const int* t;
    const float *Wg0, *bg0, *Wg1, *bg1, *Wt0, *bt0, *Wt1, *bt1;
    const float *W000, *b000, *W001, *b001, *W100, *b100, *W101, *b101;
    const float *Wo0, *bo0, *Wo1, *bo1, *Wpp, *bpp, *Wpp2, *bpp2, *a;
    int* cnt; float2* pairs;
    float *colsum, *s_src, *s_dst, *B1, *B2, *B3, *B4;
    float *out_y, *out_rep, *out_trt;
};

__global__ __launch_bounds__(256, 4) void mega(KArgs A) {
    __shared__ float smem[1536];   // 6 KB union: A:xs(1024) B:ra|rb(1024) C:rts(512) D:reps|u0s|u1s(1536)
    const int tid = threadIdx.x;
    const int sub = tid >> 6, f = tid & 63;
    cg::grid_group grid = cg::this_grid();

    // ================= Phase A: sparsify (atomic-free) + layer-1 gemm128 =================
    if (blockIdx.x == 0 && tid < 64) A.colsum[tid] = 0.0f;   // consumed in phase C
    for (int chunk = blockIdx.x; chunk < TOTAL_A; chunk += gridDim.x) {
        if (chunk < GEMM_CHUNKS) {
            int row0 = chunk * 8;
            float* xs = smem;
            ((float4*)xs)[tid] = ((const float4*)(A.x + (size_t)row0 * 128))[tid];
            __syncthreads();
            #pragma unroll
            for (int g = 0; g < 2; ++g) {
                const float* xr = xs + (g * 4 + sub) * 128;
                float aP = 0.0f, aQ = 0.0f;
                #pragma unroll 8
                for (int k = 0; k < 128; k += 4) {
                    float4 xv = *(const float4*)(xr + k);
                    aP += xv.x * A.Wg0[(k + 0) * 64 + f] + xv.y * A.Wg0[(k + 1) * 64 + f]
                        + xv.z * A.Wg0[(k + 2) * 64 + f] + xv.w * A.Wg0[(k + 3) * 64 + f];
                    aQ += xv.x * A.Wt0[(k + 0) * 64 + f] + xv.y * A.Wt0[(k + 1) * 64 + f]
                        + xv.z * A.Wt0[(k + 2) * 64 + f] + xv.w * A.Wt0[(k + 3) * 64 + f];
                }
                A.B1[(size_t)(row0 + g * 4 + sub) * 64 + f] = aP;
                A.B2[(size_t)(row0 + g * 4 + sub) * 64 + f] = aQ;
            }
            __syncthreads();   // WAR guard on xs before next chunk
        } else {
            int row = (chunk - GEMM_CHUNKS) * 4 + sub;      // one wave per adj row
            const float4* rp = A.adj4 + (size_t)row * ROW4;
            size_t base = (size_t)row * CAP;
            int count = 0;
            for (int it = 0; it < 40; ++it) {               // 40*64 = 2560 >= 2500
                int idx = it * 64 + f;
                float4 v = make_float4(0.f, 0.f, 0.f, 0.f);
                if (idx < ROW4) v = rp[idx];
                float vv[4] = {v.x, v.y, v.z, v.w};
                bool any = (v.x != 0.f) | (v.y != 0.f) | (v.z != 0.f) | (v.w != 0.f);
                if (__ballot(any)) {                         // common case: 1 ballot, no nnz
                    #pragma unroll
                    for (int l = 0; l < 4; ++l) {
                        unsigned long long b = __ballot(vv[l] != 0.f);
                        if (b) {
                            int pre = __popcll(b & ((1ull << f) - 1ull));
                            if (vv[l] != 0.f) {
                                int pos = count + pre;
                                if (pos < CAP)
                                    A.pairs[base + pos] =
                                        make_float2(__int_as_float(idx * 4 + l), vv[l]);
                            }
                            count += (int)__popcll(b);
                        }
                    }
                }
            }
            if (f == 0) A.cnt[row] = min(count, CAP);
        }
    }
    grid.sync();

    // ================= Phase B: layer-1 agg (SpMM pair) + layer-2 gemm64 pair ============
    {
        float* ra = smem; float* rb = smem + 512;
        float bo = A.bg0[f], bt = A.bt0[f];
        for (int chunk = blockIdx.x; chunk < ROW_CHUNKS; chunk += gridDim.x) {
            int row0 = chunk * 8;
            #pragma unroll
            for (int g = 0; g < 2; ++g) {
                int lr = g * 4 + sub, row = row0 + lr;
                int c = min(A.cnt[row], CAP);
                float2 pr = make_float2(0.f, 0.f);
                if (f < c) pr = A.pairs[(size_t)row * CAP + f];
                int c_l = __float_as_int(pr.x); float v_l = pr.y;
                float a0 = 0.f, a1 = 0.f, b0 = 0.f, b1 = 0.f;
                for (int p = 0; p < c; p += 8) {
                    #pragma unroll
                    for (int j = 0; j < 8; j += 2) {
                        float vv0 = __shfl(v_l, p + j, 64);     int cc0 = __shfl(c_l, p + j, 64);
                        float vv1 = __shfl(v_l, p + j + 1, 64); int cc1 = __shfl(c_l, p + j + 1, 64);
                        a0 += vv0 * A.B1[(size_t)cc0 * 64 + f];
                        b0 += vv0 * A.B2[(size_t)cc0 * 64 + f];
                        a1 += vv1 * A.B1[(size_t)cc1 * 64 + f];
                        b1 += vv1 * A.B2[(size_t)cc1 * 64 + f];
                    }
                }
                ra[lr * 64 + f] = fmaxf(a0 + a1 + bo, 0.0f);
                rb[lr * 64 + f] = fmaxf(b0 + b1 + bt, 0.0f);
            }
            __syncthreads();
            #pragma unroll
            for (int g = 0; g < 2; ++g) {
                int lr = g * 4 + sub, row = row0 + lr;
                const float* rra = ra + lr * 64;
                const float* rrb = rb + lr * 64;
                float aA = 0.f, aB = 0.f;
                #pragma unroll 8
                for (int k = 0; k < 64; k += 4) {
                    float4 va = *(const float4*)(rra + k);
                    float4 vb = *(const float4*)(rrb + k);
                    aA += va.x * A.Wg1[(k + 0) * 64 + f] + va.y * A.Wg1[(k + 1) * 64 + f]
                        + va.z * A.Wg1[(k + 2) * 64 + f] + va.w * A.Wg1[(k + 3) * 64 + f];
                    aB += vb.x * A.Wt1[(k + 0) * 64 + f] + vb.y * A.Wt1[(k + 1) * 64 + f]
                        + vb.z * A.Wt1[(k + 2) * 64 + f] + vb.w * A.Wt1[(k + 3) * 64 + f];
                }
                A.B3[(size_t)row * 64 + f] = aA;
                A.B4[(size_t)row * 64 + f] = aB;
            }
            __syncthreads();   // WAR guard on ra/rb
        }
    }
    grid.sync();

    // ================= Phase C: layer-2 agg + score + colsum + treatment =================
    {
        float* rts = smem;
        float bo = A.bg1[f], bt = A.bt1[f];
        float a0c = A.a[f], a1c = A.a[64 + f], a2c = A.a[128 + f], a3c = A.a[192 + f];
        float bp = A.bpp[f], w20 = A.Wpp2[f * 2 + 0], w21 = A.Wpp2[f * 2 + 1];
        for (int chunk = blockIdx.x; chunk < ROW_CHUNKS; chunk += gridDim.x) {
            int row0 = chunk * 8;
            #pragma unroll
            for (int g = 0; g < 2; ++g) {
                int lr = g * 4 + sub, row = row0 + lr;
                int c = min(A.cnt[row], CAP);
                float2 pr = make_float2(0.f, 0.f);
                if (f < c) pr = A.pairs[(size_t)row * CAP + f];
                int c_l = __float_as_int(pr.x); float v_l = pr.y;
                float a0 = 0.f, a1 = 0.f, b0 = 0.f, b1 = 0.f;
                for (int p = 0; p < c; p += 8) {
                    #pragma unroll
                    for (int j = 0; j < 8; j += 2) {
                        float vv0 = __shfl(v_l, p + j, 64);     int cc0 = __shfl(c_l, p + j, 64);
                        float vv1 = __shfl(v_l, p + j + 1, 64); int cc1 = __shfl(c_l, p + j + 1, 64);
                        a0 += vv0 * A.B3[(size_t)cc0 * 64 + f];
                        b0 += vv0 * A.B4[(size_t)cc0 * 64 + f];
                        a1 += vv1 * A.B3[(size_t)cc1 * 64 + f];
                        b1 += vv1 * A.B4[(size_t)cc1 * 64 + f];
                    }
                }
                float vo = fmaxf(a0 + a1 + bo, 0.0f);
                float vt = fmaxf(b0 + b1 + bt, 0.0f);
                A.B1[(size_t)row * 64 + f] = vo;    // rep_o (B1 reused)
                A.B2[(size_t)row * 64 + f] = vt;    // rep_t (B2 reused)
                rts[lr * 64 + f] = vt;
                float ps = wave_sum(vo * a0c + vt * a1c);
                float pd = wave_sum(vo * a2c + vt * a3c);
                if (f == 0) { A.s_src[row] = ps; A.s_dst[row] = pd; }
            }
            __syncthreads();
            if (sub == 0) {                         // one block-reduced atomic per feature
                float cs = 0.0f;
                #pragma unroll
                for (int lr = 0; lr < 8; ++lr) cs += rts[lr * 64 + f];
                atomicAdd(&A.colsum[f], cs);
            }
            #pragma unroll
            for (int g = 0; g < 2; ++g) {
                int lr = g * 4 + sub, row = row0 + lr;
                const float* rr = rts + lr * 64;
                float u = bp;
                #pragma unroll 8
                for (int k = 0; k < 64; k += 4) {
                    float4 rv = *(const float4*)(rr + k);
                    u += rv.x * A.Wpp[(k + 0) * 64 + f] + rv.y * A.Wpp[(k + 1) * 64 + f]
                       + rv.z * A.Wpp[(k + 2) * 64 + f] + rv.w * A.Wpp[(k + 3) * 64 + f];
                }
                float p0 = wave_sum(u * w20);
                float p1 = wave_sum(u * w21);
                if (f == 0) {
                    A.out_trt[(size_t)row * 2 + 0] = 1.0f / (1.0f + expf(-(p0 + A.bpp2[0])));
                    A.out_trt[(size_t)row * 2 + 1] = 1.0f / (1.0f + expf(-(p1 + A.bpp2[1])));
                }
            }
            __syncthreads();   // WAR guard on rts
        }
    }
    grid.sync();

    // ================= Phase D: attention + outcome heads + select =======================
    {
        float* reps = smem; float* u0s = smem + 512; float* u1s = smem + 1024;
        float csf = A.colsum[f];
        float bA = A.b000[f], bB = A.b100[f];
        float bC = A.b001[f], bD = A.b101[f], wo0 = A.Wo0[f], wo1 = A.Wo1[f];
        for (int chunk = blockIdx.x; chunk < ROW_CHUNKS; chunk += gridDim.x) {
            int row0 = chunk * 8;
            #pragma unroll
            for (int g = 0; g < 2; ++g) {
                int lr = g * 4 + sub, row = row0 + lr;
                int c = min(A.cnt[row], CAP);
                float ssrc = A.s_src[row];
                int   col_l = (f < c) ? __float_as_int(A.pairs[(size_t)row * CAP + f].x) : 0;
                float s_l   = (f < c) ? ssrc + A.s_dst[col_l] : -1e30f;
                float m = fmaxf(wave_max(s_l), 0.0f);   // zeros of the dense row join the max
                float e_l = (f < c) ? expf(s_l - m) : 0.0f;
                float em = expf(-m);
                float Z = wave_sum(e_l) + (float)(N_NODES - c) * em;
                float g_l = (f < c) ? (e_l - em) : 0.0f;
                float a0 = 0.f, a1 = 0.f, a2 = 0.f, a3 = 0.f;
                for (int p = 0; p < c; p += 8) {
                    #pragma unroll
                    for (int j = 0; j < 8; j += 4) {
                        float g0 = __shfl(g_l, p + j + 0, 64); int c0 = __shfl(col_l, p + j + 0, 64);
                        float g1 = __shfl(g_l, p + j + 1, 64); int c1 = __shfl(col_l, p + j + 1, 64);
                        float g2 = __shfl(g_l, p + j + 2, 64); int c2 = __shfl(col_l, p + j + 2, 64);
                        float g3 = __shfl(g_l, p + j + 3, 64); int c3 = __shfl(col_l, p + j + 3, 64);
                        a0 += g0 * A.B2[(size_t)c0 * 64 + f];
                        a1 += g1 * A.B2[(size_t)c1 * 64 + f];
                        a2 += g2 * A.B2[(size_t)c2 * 64 + f];
                        a3 += g3 * A.B2[(size_t)c3 * 64 + f];
                    }
                }
                float outv = ((a0 + a1 + a2 + a3) + em * csf) / Z + A.B1[(size_t)row * 64 + f];
                A.out_rep[(size_t)row * 64 + f] = outv;
                reps[lr * 64 + f] = outv;
            }
            __syncthreads();
            #pragma unroll
            for (int g = 0; g < 2; ++g) {
                int lr = g * 4 + sub;
                const float* rr = reps + lr * 64;
                float u0 = bA, u1 = bB;
                #pragma unroll 8
                for (int k = 0; k < 64; k += 4) {
                    float4 rv = *(const float4*)(rr + k);
                    u0 += rv.x * A.W000[(k + 0) * 64 + f] + rv.y * A.W000[(k + 1) * 64 + f]
                        + rv.z * A.W000[(k + 2) * 64 + f] + rv.w * A.W000[(k + 3) * 64 + f];
                    u1 += rv.x * A.W100[(k + 0) * 64 + f] + rv.y * A.W100[(k + 1) * 64 + f]
                        + rv.z * A.W100[(k + 2) * 64 + f] + rv.w * A.W100[(k + 3) * 64 + f];
                }
                u0s[lr * 64 + f] = fmaxf(u0, 0.0f);
                u1s[lr * 64 + f] = fmaxf(u1, 0.0f);
            }
            __syncthreads();
            #pragma unroll
            for (int g = 0; g < 2; ++g) {
                int lr = g * 4 + sub, row = row0 + lr;
                const float* r0 = u0s + lr * 64;
                const float* r1 = u1s + lr * 64;
                float v0 = bC, v1 = bD;
                #pragma unroll 8
                for (int k = 0; k < 64; k += 4) {
                    float4 q0 = *(const float4*)(r0 + k);
                    float4 q1 = *(const float4*)(r1 + k);
                    v0 += q0.x * A.W001[(k + 0) * 64 + f] + q0.y * A.W001[(k + 1) * 64 + f]
                        + q0.z * A.W001[(k + 2) * 64 + f] + q0.w * A.W001[(k + 3) * 64 + f];
                    v1 += q1.x * A.W101[(k + 0) * 64 + f] + q1.y * A.W101[(k + 1) * 64 + f]
                        + q1.z * A.W101[(k + 2) * 64 + f] + q1.w * A.W101[(k + 3) * 64 + f];
                }
                float y0 = wave_sum(fmaxf(v0, 0.0f) * wo0);
                float y1 = wave_sum(fmaxf(v1, 0.0f) * wo1);
                if (f == 0)
                    A.out_y[row] = (A.t[row] > 0) ? (y1 + A.bo1[0]) : (y0 + A.bo0[0]);
            }
            __syncthreads();   // WAR guard on reps/u0s/u1s
        }
    }
}

// ---------------- launch ----------------

extern "C" void kernel_launch(void* const* d_in, const int* in_sizes, int n_in,
                              void* d_out, int out_size, void* d_ws, size_t ws_size,
                              hipStream_t stream) {
    float* ws = (float*)d_ws;
    KArgs ka;
    ka.x    = (const float*)d_in[0];
    ka.adj4 = (const float4*)d_in[1];
    ka.t    = (const int*)d_in[2];
    ka.Wg0  = (const float*)d_in[3];  ka.bg0  = (const float*)d_in[4];
    ka.Wg1  = (const float*)d_in[5];  ka.bg1  = (const float*)d_in[6];
    ka.Wt0  = (const float*)d_in[7];  ka.bt0  = (const float*)d_in[8];
    ka.Wt1  = (const float*)d_in[9];  ka.bt1  = (const float*)d_in[10];
    ka.W000 = (const float*)d_in[11]; ka.b000 = (const float*)d_in[12];
    ka.W001 = (const float*)d_in[13]; ka.b001 = (const float*)d_in[14];
    ka.W100 = (const float*)d_in[15]; ka.b100 = (const float*)d_in[16];
    ka.W101 = (const float*)d_in[17]; ka.b101 = (const float*)d_in[18];
    ka.Wo0  = (const float*)d_in[19]; ka.bo0  = (const float*)d_in[20];
    ka.Wo1  = (const float*)d_in[21]; ka.bo1  = (const float*)d_in[22];
    ka.Wpp  = (const float*)d_in[23]; ka.bpp  = (const float*)d_in[24];
    ka.Wpp2 = (const float*)d_in[25]; ka.bpp2 = (const float*)d_in[26];
    ka.a    = (const float*)d_in[27];
    ka.cnt    = (int*)(ws + OFF_CNT);
    ka.colsum = ws + OFF_COLSUM;
    ka.s_src  = ws + OFF_SSRC;
    ka.s_dst  = ws + OFF_SDST;
    ka.pairs  = (float2*)(ws + OFF_PAIRS);
    ka.B1     = ws + OFF_B1;
    ka.B2     = ws + OFF_B2;
    ka.B3     = ws + OFF_B3;
    ka.B4     = ws + OFF_B4;
    ka.out_y   = (float*)d_out;                            // [N]
    ka.out_rep = (float*)d_out + N_NODES;                  // [N,64]
    ka.out_trt = (float*)d_out + N_NODES + N_NODES * 64;   // [N,2]

    int nb = 0;
    hipOccupancyMaxActiveBlocksPerMultiprocessor(&nb, (const void*)mega, 256, 0);
    if (nb <= 0) nb = 4;
    int grid = nb * 256;
    if (grid > MAX_GRID) grid = MAX_GRID;

    void* kp[] = { (void*)&ka };
    hipLaunchCooperativeKernel((const void*)mega, dim3(grid), dim3(256), kp, 0, stream);
}

// Round 5
// 682.576 us; speedup vs baseline: 1.4260x; 1.4260x over previous
//
#include <hip/hip_runtime.h>
#include <hip/hip_bf16.h>

#define N_NODES 10000
#define ROW4    2500          // float4 per adj row
#define CAP     64            // max nnz stored/row (Binomial(10000,0.002) tail past 64 ~1e-15)
#define GEMM_BLOCKS 1250      // k1 block-range split: [0,1250) gemm128, [1250,3750) sparsify

// ---- workspace layout (float-element offsets) ----
#define OFF_CNT     0                         // int[10000]
#define OFF_COLSUM  10000                     // float[64]
#define OFF_SSRC    10064                     // float[10000]
#define OFF_SDST    20064                     // float[10000]
#define OFF_PAIRS   30064                     // float2[10000*64] (30064*4 % 8 == 0)
#define OFF_B1      1310064                   // float[10000*64]
#define OFF_B2      1950064
#define OFF_B3      2590064
#define OFF_B4      3230064

__device__ __forceinline__ float wave_sum(float v) {
    #pragma unroll
    for (int off = 32; off >= 1; off >>= 1) v += __shfl_xor(v, off, 64);
    return v;
}
__device__ __forceinline__ float wave_max(float v) {
    #pragma unroll
    for (int off = 32; off >= 1; off >>= 1) v = fmaxf(v, __shfl_xor(v, off, 64));
    return v;
}

// ---------------- K1: sparsify (8 loads in flight) + layer-1 gemm128, fused ----
// Sparsify fix vs R3/R4: the ballot consumed each load immediately -> vmcnt(0)
// every iteration -> ONE outstanding load/wave -> 450 GB/s. Now 8 independent
// float4 loads are issued per batch before any ballot touches them.
__global__ void k1_fused(const float4* __restrict__ adj4, const float* __restrict__ x,
                         const float* __restrict__ Wg0, const float* __restrict__ Wt0,
                         int* __restrict__ cnt, float2* __restrict__ pairs,
                         float* __restrict__ colsum,
                         float* __restrict__ P, float* __restrict__ Q) {
    __shared__ float xs[8 * 128];
    int tid = threadIdx.x;
    if (blockIdx.x < GEMM_BLOCKS) {
        int row0 = blockIdx.x * 8;
        ((float4*)xs)[tid] = ((const float4*)(x + (size_t)row0 * 128))[tid];
        if (blockIdx.x == 0 && tid < 64) colsum[tid] = 0.0f;   // consumed by K3
        __syncthreads();
        int sub = tid >> 6, f = tid & 63;
        #pragma unroll
        for (int g = 0; g < 2; ++g) {
            const float* xr = xs + (g * 4 + sub) * 128;
            float aP = 0.0f, aQ = 0.0f;
            #pragma unroll 8
            for (int k = 0; k < 128; k += 4) {
                float4 xv = *(const float4*)(xr + k);
                aP += xv.x * Wg0[(k + 0) * 64 + f] + xv.y * Wg0[(k + 1) * 64 + f]
                    + xv.z * Wg0[(k + 2) * 64 + f] + xv.w * Wg0[(k + 3) * 64 + f];
                aQ += xv.x * Wt0[(k + 0) * 64 + f] + xv.y * Wt0[(k + 1) * 64 + f]
                    + xv.z * Wt0[(k + 2) * 64 + f] + xv.w * Wt0[(k + 3) * 64 + f];
            }
            P[(size_t)(row0 + g * 4 + sub) * 64 + f] = aP;
            Q[(size_t)(row0 + g * 4 + sub) * 64 + f] = aQ;
        }
    } else {
        int lane = tid & 63, w = tid >> 6;
        int row = (blockIdx.x - GEMM_BLOCKS) * 4 + w;       // one wave per adj row
        const float4* rp = adj4 + (size_t)row * ROW4;
        size_t base = (size_t)row * CAP;
        int count = 0;
        for (int it = 0; it < 40; it += 8) {                // 5 batches x 8 = 40 >= 2500/64
            float4 v[8];
            #pragma unroll
            for (int j = 0; j < 8; ++j) {                   // 8 independent loads in flight
                int idx = (it + j) * 64 + lane;
                v[j] = make_float4(0.f, 0.f, 0.f, 0.f);
                if (idx < ROW4) v[j] = rp[idx];
            }
            #pragma unroll
            for (int j = 0; j < 8; ++j) {
                int idx = (it + j) * 64 + lane;
                float vv[4] = {v[j].x, v[j].y, v[j].z, v[j].w};
                bool any = (vv[0] != 0.f) | (vv[1] != 0.f) | (vv[2] != 0.f) | (vv[3] != 0.f);
                if (__ballot(any)) {                        // common case: whole wave zero
                    #pragma unroll
                    for (int l = 0; l < 4; ++l) {
                        unsigned long long b = __ballot(vv[l] != 0.f);
                        if (b) {
                            int pre = __popcll(b & ((1ull << lane) - 1ull));
                            if (vv[l] != 0.f) {
                                int pos = count + pre;
                                if (pos < CAP)
                                    pairs[base + pos] =
                                        make_float2(__int_as_float(idx * 4 + l), vv[l]);
                            }
                            count += (int)__popcll(b);
                        }
                    }
                }
            }
        }
        if (lane == 0) cnt[row] = min(count, CAP);
    }
}

// ---------------- K2: layer-1 agg (SpMM pair) + layer-2 gemm64 pair ------------
__global__ void k2_agg_gemm(const int* __restrict__ cnt, const float2* __restrict__ pairs,
                            const float* __restrict__ P, const float* __restrict__ Q,
                            const float* __restrict__ bg0, const float* __restrict__ bt0,
                            const float* __restrict__ Wg1, const float* __restrict__ Wt1,
                            float* __restrict__ P2, float* __restrict__ Q2) {
    __shared__ float ra[8 * 64], rb[8 * 64];
    int tid = threadIdx.x, row0 = blockIdx.x * 8, sub = tid >> 6, f = tid & 63;
    float bo = bg0[f], bt = bt0[f];
    #pragma unroll
    for (int g = 0; g < 2; ++g) {
        int lr = g * 4 + sub, row = row0 + lr;
        int c = min(cnt[row], CAP);
        float2 pr = make_float2(0.f, 0.f);
        if (f < c) pr = pairs[(size_t)row * CAP + f];
        int c_l = __float_as_int(pr.x); float v_l = pr.y;
        float a0 = 0.f, a1 = 0.f, b0 = 0.f, b1 = 0.f;
        for (int p = 0; p < c; p += 8) {
            #pragma unroll
            for (int j = 0; j < 8; j += 2) {
                float vv0 = __shfl(v_l, p + j, 64);     int cc0 = __shfl(c_l, p + j, 64);
                float vv1 = __shfl(v_l, p + j + 1, 64); int cc1 = __shfl(c_l, p + j + 1, 64);
                a0 += vv0 * P[(size_t)cc0 * 64 + f];
                b0 += vv0 * Q[(size_t)cc0 * 64 + f];
                a1 += vv1 * P[(size_t)cc1 * 64 + f];
                b1 += vv1 * Q[(size_t)cc1 * 64 + f];
            }
        }
        ra[lr * 64 + f] = fmaxf(a0 + a1 + bo, 0.0f);
        rb[lr * 64 + f] = fmaxf(b0 + b1 + bt, 0.0f);
    }
    __syncthreads();
    #pragma unroll
    for (int g = 0; g < 2; ++g) {
        int lr = g * 4 + sub, row = row0 + lr;
        const float* rra = ra + lr * 64;
        const float* rrb = rb + lr * 64;
        float aA = 0.f, aB = 0.f;
        #pragma unroll 8
        for (int k = 0; k < 64; k += 4) {
            float4 va = *(const float4*)(rra + k);
            float4 vb = *(const float4*)(rrb + k);
            aA += va.x * Wg1[(k + 0) * 64 + f] + va.y * Wg1[(k + 1) * 64 + f]
                + va.z * Wg1[(k + 2) * 64 + f] + va.w * Wg1[(k + 3) * 64 + f];
            aB += vb.x * Wt1[(k + 0) * 64 + f] + vb.y * Wt1[(k + 1) * 64 + f]
                + vb.z * Wt1[(k + 2) * 64 + f] + vb.w * Wt1[(k + 3) * 64 + f];
        }
        P2[(size_t)row * 64 + f] = aA;
        Q2[(size_t)row * 64 + f] = aB;
    }
}

// ---------------- K3: layer-2 agg + score + colsum + treatment -----------------
__global__ void k3_agg_score(const int* __restrict__ cnt, const float2* __restrict__ pairs,
                             const float* __restrict__ P2, const float* __restrict__ Q2,
                             const float* __restrict__ bg1, const float* __restrict__ bt1,
                             const float* __restrict__ a,
                             const float* __restrict__ Wpp, const float* __restrict__ bpp,
                             const float* __restrict__ Wpp2, const float* __restrict__ bpp2,
                             float* __restrict__ rep_o, float* __restrict__ rep_t,
                             float* __restrict__ s_src, float* __restrict__ s_dst,
                             float* __restrict__ colsum, float* __restrict__ out_trt) {
    __shared__ float rts[8 * 64];
    int tid = threadIdx.x, row0 = blockIdx.x * 8, sub = tid >> 6, f = tid & 63;
    float bo = bg1[f], bt = bt1[f];
    float a0c = a[f], a1c = a[64 + f], a2c = a[128 + f], a3c = a[192 + f];
    #pragma unroll
    for (int g = 0; g < 2; ++g) {
        int lr = g * 4 + sub, row = row0 + lr;
        int c = min(cnt[row], CAP);
        float2 pr = make_float2(0.f, 0.f);
        if (f < c) pr = pairs[(size_t)row * CAP + f];
        int c_l = __float_as_int(pr.x); float v_l = pr.y;
        float a0 = 0.f, a1 = 0.f, b0 = 0.f, b1 = 0.f;
        for (int p = 0; p < c; p += 8) {
            #pragma unroll
            for (int j = 0; j < 8; j += 2) {
                float vv0 = __shfl(v_l, p + j, 64);     int cc0 = __shfl(c_l, p + j, 64);
                float vv1 = __shfl(v_l, p + j + 1, 64); int cc1 = __shfl(c_l, p + j + 1, 64);
                a0 += vv0 * P2[(size_t)cc0 * 64 + f];
                b0 += vv0 * Q2[(size_t)cc0 * 64 + f];
                a1 += vv1 * P2[(size_t)cc1 * 64 + f];
                b1 += vv1 * Q2[(size_t)cc1 * 64 + f];
            }
        }
        float vo = fmaxf(a0 + a1 + bo, 0.0f);
        float vt = fmaxf(b0 + b1 + bt, 0.0f);
        rep_o[(size_t)row * 64 + f] = vo;
        rep_t[(size_t)row * 64 + f] = vt;
        rts[lr * 64 + f] = vt;
        float ps = wave_sum(vo * a0c + vt * a1c);
        float pd = wave_sum(vo * a2c + vt * a3c);
        if (f == 0) { s_src[row] = ps; s_dst[row] = pd; }
    }
    __syncthreads();
    if (sub == 0) {                       // one block-reduced atomic per feature
        float cs = 0.0f;
        #pragma unroll
        for (int lr = 0; lr < 8; ++lr) cs += rts[lr * 64 + f];
        atomicAdd(&colsum[f], cs);
    }
    float bp = bpp[f], w20 = Wpp2[f * 2 + 0], w21 = Wpp2[f * 2 + 1];
    #pragma unroll
    for (int g = 0; g < 2; ++g) {
        int lr = g * 4 + sub, row = row0 + lr;
        const float* rr = rts + lr * 64;
        float u = bp;
        #pragma unroll 8
        for (int k = 0; k < 64; k += 4) {
            float4 rv = *(const float4*)(rr + k);
            u += rv.x * Wpp[(k + 0) * 64 + f] + rv.y * Wpp[(k + 1) * 64 + f]
               + rv.z * Wpp[(k + 2) * 64 + f] + rv.w * Wpp[(k + 3) * 64 + f];
        }
        float p0 = wave_sum(u * w20);
        float p1 = wave_sum(u * w21);
        if (f == 0) {
            out_trt[(size_t)row * 2 + 0] = 1.0f / (1.0f + expf(-(p0 + bpp2[0])));
            out_trt[(size_t)row * 2 + 1] = 1.0f / (1.0f + expf(-(p1 + bpp2[1])));
        }
    }
}

// ---------------- K4: attention + outcome heads + select ----------------------
__global__ void k4_attn_heads(const int* __restrict__ cnt, const float2* __restrict__ pairs,
                              const float* __restrict__ s_src, const float* __restrict__ s_dst,
                              const float* __restrict__ colsum,
                              const float* __restrict__ rep_o, const float* __restrict__ rep_t,
                              const float* __restrict__ W000, const float* __restrict__ b000,
                              const float* __restrict__ W001, const float* __restrict__ b001,
                              const float* __restrict__ W100, const float* __restrict__ b100,
                              const float* __restrict__ W101, const float* __restrict__ b101,
                              const float* __restrict__ Wo0, const float* __restrict__ bo0,
                              const float* __restrict__ Wo1, const float* __restrict__ bo1,
                              const int* __restrict__ t,
                              float* __restrict__ out_y, float* __restrict__ out_rep) {
    __shared__ float reps[8 * 64], u0s[8 * 64], u1s[8 * 64];
    int tid = threadIdx.x, row0 = blockIdx.x * 8, sub = tid >> 6, f = tid & 63;
    float csf = colsum[f];
    #pragma unroll
    for (int g = 0; g < 2; ++g) {
        int lr = g * 4 + sub, row = row0 + lr;
        int c = min(cnt[row], CAP);
        float ssrc = s_src[row];
        int   col_l = (f < c) ? __float_as_int(pairs[(size_t)row * CAP + f].x) : 0;
        float s_l   = (f < c) ? ssrc + s_dst[col_l] : -1e30f;
        float m = fmaxf(wave_max(s_l), 0.0f);     // zeros of the dense row join the max
        float e_l = (f < c) ? expf(s_l - m) : 0.0f;
        float em = expf(-m);
        float Z = wave_sum(e_l) + (float)(N_NODES - c) * em;
        float g_l = (f < c) ? (e_l - em) : 0.0f;  // lanes >= c contribute 0 in overshoot
        float a0 = 0.f, a1 = 0.f, a2 = 0.f, a3 = 0.f;
        for (int p = 0; p < c; p += 8) {
            #pragma unroll
            for (int j = 0; j < 8; j += 4) {
                float g0 = __shfl(g_l, p + j + 0, 64); int c0 = __shfl(col_l, p + j + 0, 64);
                float g1 = __shfl(g_l, p + j + 1, 64); int c1 = __shfl(col_l, p + j + 1, 64);
                float g2 = __shfl(g_l, p + j + 2, 64); int c2 = __shfl(col_l, p + j + 2, 64);
                float g3 = __shfl(g_l, p + j + 3, 64); int c3 = __shfl(col_l, p + j + 3, 64);
                a0 += g0 * rep_t[(size_t)c0 * 64 + f];
                a1 += g1 * rep_t[(size_t)c1 * 64 + f];
                a2 += g2 * rep_t[(size_t)c2 * 64 + f];
                a3 += g3 * rep_t[(size_t)c3 * 64 + f];
            }
        }
        float outv = ((a0 + a1 + a2 + a3) + em * csf) / Z + rep_o[(size_t)row * 64 + f];
        out_rep[(size_t)row * 64 + f] = outv;
        reps[lr * 64 + f] = outv;
    }
    __syncthreads();
    float bA = b000[f], bB = b100[f];
    #pragma unroll
    for (int g = 0; g < 2; ++g) {
        int lr = g * 4 + sub;
        const float* rr = reps + lr * 64;
        float u0 = bA, u1 = bB;
        #pragma unroll 8
        for (int k = 0; k < 64; k += 4) {
            float4 rv = *(const float4*)(rr + k);
            u0 += rv.x * W000[(k + 0) * 64 + f] + rv.y * W000[(k + 1) * 64 + f]
                + rv.z * W000[(k + 2) * 64 + f] + rv.w * W000[(k + 3) * 64 + f];
            u1 += rv.x * W100[(k + 0) * 64 + f] + rv.y * W100[(k + 1) * 64 + f]
                + rv.z * W100[(k + 2) * 64 + f] + rv.w * W100[(k + 3) * 64 + f];
        }
        u0s[lr * 64 + f] = fmaxf(u0, 0.0f);
        u1s[lr * 64 + f] = fmaxf(u1, 0.0f);
    }
    __syncthreads();
    float bC = b001[f], bD = b101[f], wo0 = Wo0[f], wo1 = Wo1[f];
    #pragma unroll
    for (int g = 0; g < 2; ++g) {
        int lr = g * 4 + sub, row = row0 + lr;
        const float* r0 = u0s + lr * 64;
        const float* r1 = u1s + lr * 64;
        float v0 = bC, v1 = bD;
        #pragma unroll 8
        for (int k = 0; k < 64; k += 4) {
            float4 q0 = *(const float4*)(r0 + k);
            float4 q1 = *(const float4*)(r1 + k);
            v0 += q0.x * W001[(k + 0) * 64 + f] + q0.y * W001[(k + 1) * 64 + f]
                + q0.z * W001[(k + 2) * 64 + f] + q0.w * W001[(k + 3) * 64 + f];
            v1 += q1.x * W101[(k + 0) * 64 + f] + q1.y * W101[(k + 1) * 64 + f]
                + q1.z * W101[(k + 2) * 64 + f] + q1.w * W101[(k + 3) * 64 + f];
        }
        float y0 = wave_sum(fmaxf(v0, 0.0f) * wo0);
        float y1 = wave_sum(fmaxf(v1, 0.0f) * wo1);
        if (f == 0)
            out_y[row] = (t[row] > 0) ? (y1 + bo1[0]) : (y0 + bo0[0]);
    }
}

// ---------------- launch ----------------

extern "C" void kernel_launch(void* const* d_in, const int* in_sizes, int n_in,
                              void* d_out, int out_size, void* d_ws, size_t ws_size,
                              hipStream_t stream) {
    const float* x    = (const float*)d_in[0];
    const float* adj  = (const float*)d_in[1];
    const int*   t    = (const int*)d_in[2];
    const float* Wg0  = (const float*)d_in[3];
    const float* bg0  = (const float*)d_in[4];
    const float* Wg1  = (const float*)d_in[5];
    const float* bg1  = (const float*)d_in[6];
    const float* Wt0  = (const float*)d_in[7];
    const float* bt0  = (const float*)d_in[8];
    const float* Wt1  = (const float*)d_in[9];
    const float* bt1  = (const float*)d_in[10];
    const float* W000 = (const float*)d_in[11];
    const float* b000 = (const float*)d_in[12];
    const float* W001 = (const float*)d_in[13];
    const float* b001 = (const float*)d_in[14];
    const float* W100 = (const float*)d_in[15];
    const float* b100 = (const float*)d_in[16];
    const float* W101 = (const float*)d_in[17];
    const float* b101 = (const float*)d_in[18];
    const float* Wo0  = (const float*)d_in[19];
    const float* bo0  = (const float*)d_in[20];
    const float* Wo1  = (const float*)d_in[21];
    const float* bo1  = (const float*)d_in[22];
    const float* Wpp  = (const float*)d_in[23];
    const float* bpp  = (const float*)d_in[24];
    const float* Wpp2 = (const float*)d_in[25];
    const float* bpp2 = (const float*)d_in[26];
    const float* a    = (const float*)d_in[27];

    float* ws = (float*)d_ws;
    int*    cnt    = (int*)(ws + OFF_CNT);
    float*  colsum = ws + OFF_COLSUM;
    float*  s_src  = ws + OFF_SSRC;
    float*  s_dst  = ws + OFF_SDST;
    float2* pairs  = (float2*)(ws + OFF_PAIRS);
    float*  B1     = ws + OFF_B1;   // x@Wg0 -> (K3) rep_o
    float*  B2     = ws + OFF_B2;   // x@Wt0 -> (K3) rep_t
    float*  B3     = ws + OFF_B3;   // layer2 pre-agg outcome
    float*  B4     = ws + OFF_B4;   // layer2 pre-agg treatment

    float* out_y   = (float*)d_out;                            // [N]
    float* out_rep = (float*)d_out + N_NODES;                  // [N,64]
    float* out_trt = (float*)d_out + N_NODES + N_NODES * 64;   // [N,2]

    k1_fused<<<GEMM_BLOCKS + 2500, 256, 0, stream>>>((const float4*)adj, x, Wg0, Wt0,
                                                     cnt, pairs, colsum, B1, B2);
    k2_agg_gemm<<<1250, 256, 0, stream>>>(cnt, pairs, B1, B2, bg0, bt0, Wg1, Wt1, B3, B4);
    k3_agg_score<<<1250, 256, 0, stream>>>(cnt, pairs, B3, B4, bg1, bt1, a,
                                           Wpp, bpp, Wpp2, bpp2,
                                           B1, B2, s_src, s_dst, colsum, out_trt);
    k4_attn_heads<<<1250, 256, 0, stream>>>(cnt, pairs, s_src, s_dst, colsum, B1, B2,
                                            W000, b000, W001, b001,
                                            W100, b100, W101, b101,
                                            Wo0, bo0, Wo1, bo1, t, out_y, out_rep);
}

// Round 7
// 655.665 us; speedup vs baseline: 1.4845x; 1.0410x over previous
//
#include <hip/hip_runtime.h>
#include <hip/hip_bf16.h>

#define N_NODES 10000
#define ROW4    2500          // float4 per adj row
#define CAP     64            // max nnz stored/row (Binomial(10000,0.002) tail past 64 ~1e-15)
#define SPAR_BLOCKS 2500      // k1 blocks [0,2500): sparsify (launch first -> HBM stream starts first)
#define TOTAL_K1    3750      // + 1250 gemm128 blocks

typedef float fx4 __attribute__((ext_vector_type(4)));   // native vec type for nontemporal builtin

// ---- workspace layout (float-element offsets) ----
#define OFF_CNT     0                         // int[10000]
#define OFF_COLSUM  10000                     // float[64]
#define OFF_SSRC    10064                     // float[10000]
#define OFF_SDST    20064                     // float[10000]
#define OFF_PAIRS   30064                     // float2[10000*64] (30064*4 % 8 == 0)
#define OFF_B1      1310064                   // float[10000*64]
#define OFF_B2      1950064
#define OFF_B3      2590064
#define OFF_B4      3230064

__device__ __forceinline__ float wave_sum(float v) {
    #pragma unroll
    for (int off = 32; off >= 1; off >>= 1) v += __shfl_xor(v, off, 64);
    return v;
}
__device__ __forceinline__ float wave_max(float v) {
    #pragma unroll
    for (int off = 32; off >= 1; off >>= 1) v = fmaxf(v, __shfl_xor(v, off, 64));
    return v;
}

// ---------------- K1: sparsify (blocks first, nt loads) + layer-1 gemm128 ------
// adj is read exactly once -> nontemporal loads keep the 400 MB stream from
// evicting x/W working sets of the co-resident gemm blocks out of L2.
__global__ void k1_fused(const fx4* __restrict__ adj4, const float* __restrict__ x,
                         const float* __restrict__ Wg0, const float* __restrict__ Wt0,
                         int* __restrict__ cnt, float2* __restrict__ pairs,
                         float* __restrict__ colsum,
                         float* __restrict__ P, float* __restrict__ Q) {
    __shared__ float xs[8 * 128];
    int tid = threadIdx.x;
    if (blockIdx.x < SPAR_BLOCKS) {
        int lane = tid & 63, w = tid >> 6;
        int row = blockIdx.x * 4 + w;                       // one wave per adj row
        if (blockIdx.x == 0 && tid < 64) colsum[tid] = 0.0f;   // consumed by K3
        const fx4* rp = adj4 + (size_t)row * ROW4;
        size_t base = (size_t)row * CAP;
        int count = 0;
        for (int it = 0; it < 40; it += 8) {                // 5 batches x 8 loads in flight
            fx4 v[8];
            #pragma unroll
            for (int j = 0; j < 8; ++j) {
                int idx = (it + j) * 64 + lane;
                v[j] = (fx4){0.f, 0.f, 0.f, 0.f};
                if (idx < ROW4) v[j] = __builtin_nontemporal_load(rp + idx);
            }
            #pragma unroll
            for (int j = 0; j < 8; ++j) {
                int idx = (it + j) * 64 + lane;
                float vv[4] = {v[j].x, v[j].y, v[j].z, v[j].w};
                bool any = (vv[0] != 0.f) | (vv[1] != 0.f) | (vv[2] != 0.f) | (vv[3] != 0.f);
                if (__ballot(any)) {                        // common case: whole wave zero
                    #pragma unroll
                    for (int l = 0; l < 4; ++l) {
                        unsigned long long b = __ballot(vv[l] != 0.f);
                        if (b) {
                            int pre = __popcll(b & ((1ull << lane) - 1ull));
                            if (vv[l] != 0.f) {
                                int pos = count + pre;
                                if (pos < CAP)
                                    pairs[base + pos] =
                                        make_float2(__int_as_float(idx * 4 + l), vv[l]);
                            }
                            count += (int)__popcll(b);
                        }
                    }
                }
            }
        }
        if (lane == 0) cnt[row] = min(count, CAP);
    } else {
        int row0 = (blockIdx.x - SPAR_BLOCKS) * 8;
        ((float4*)xs)[tid] = ((const float4*)(x + (size_t)row0 * 128))[tid];
        __syncthreads();
        int sub = tid >> 6, f = tid & 63;
        #pragma unroll
        for (int g = 0; g < 2; ++g) {
            const float* xr = xs + (g * 4 + sub) * 128;
            float aP = 0.0f, aQ = 0.0f;
            #pragma unroll 8
            for (int k = 0; k < 128; k += 4) {
                float4 xv = *(const float4*)(xr + k);
                aP += xv.x * Wg0[(k + 0) * 64 + f] + xv.y * Wg0[(k + 1) * 64 + f]
                    + xv.z * Wg0[(k + 2) * 64 + f] + xv.w * Wg0[(k + 3) * 64 + f];
                aQ += xv.x * Wt0[(k + 0) * 64 + f] + xv.y * Wt0[(k + 1) * 64 + f]
                    + xv.z * Wt0[(k + 2) * 64 + f] + xv.w * Wt0[(k + 3) * 64 + f];
            }
            P[(size_t)(row0 + g * 4 + sub) * 64 + f] = aP;
            Q[(size_t)(row0 + g * 4 + sub) * 64 + f] = aQ;
        }
    }
}

// ---------------- K2: layer-1 agg (SpMM pair) + layer-2 gemm64 pair ------------
__global__ void k2_agg_gemm(const int* __restrict__ cnt, const float2* __restrict__ pairs,
                            const float* __restrict__ P, const float* __restrict__ Q,
                            const float* __restrict__ bg0, const float* __restrict__ bt0,
                            const float* __restrict__ Wg1, const float* __restrict__ Wt1,
                            float* __restrict__ P2, float* __restrict__ Q2) {
    __shared__ float ra[8 * 64], rb[8 * 64];
    int tid = threadIdx.x, row0 = blockIdx.x * 8, sub = tid >> 6, f = tid & 63;
    float bo = bg0[f], bt = bt0[f];
    #pragma unroll
    for (int g = 0; g < 2; ++g) {
        int lr = g * 4 + sub, row = row0 + lr;
        int c = min(cnt[row], CAP);
        float2 pr = make_float2(0.f, 0.f);
        if (f < c) pr = pairs[(size_t)row * CAP + f];
        int c_l = __float_as_int(pr.x); float v_l = pr.y;
        float a0 = 0.f, a1 = 0.f, b0 = 0.f, b1 = 0.f;
        for (int p = 0; p < c; p += 8) {
            #pragma unroll
            for (int j = 0; j < 8; j += 2) {
                float vv0 = __shfl(v_l, p + j, 64);     int cc0 = __shfl(c_l, p + j, 64);
                float vv1 = __shfl(v_l, p + j + 1, 64); int cc1 = __shfl(c_l, p + j + 1, 64);
                a0 += vv0 * P[(size_t)cc0 * 64 + f];
                b0 += vv0 * Q[(size_t)cc0 * 64 + f];
                a1 += vv1 * P[(size_t)cc1 * 64 + f];
                b1 += vv1 * Q[(size_t)cc1 * 64 + f];
            }
        }
        ra[lr * 64 + f] = fmaxf(a0 + a1 + bo, 0.0f);
        rb[lr * 64 + f] = fmaxf(b0 + b1 + bt, 0.0f);
    }
    __syncthreads();
    #pragma unroll
    for (int g = 0; g < 2; ++g) {
        int lr = g * 4 + sub, row = row0 + lr;
        const float* rra = ra + lr * 64;
        const float* rrb = rb + lr * 64;
        float aA = 0.f, aB = 0.f;
        #pragma unroll 8
        for (int k = 0; k < 64; k += 4) {
            float4 va = *(const float4*)(rra + k);
            float4 vb = *(const float4*)(rrb + k);
            aA += va.x * Wg1[(k + 0) * 64 + f] + va.y * Wg1[(k + 1) * 64 + f]
                + va.z * Wg1[(k + 2) * 64 + f] + va.w * Wg1[(k + 3) * 64 + f];
            aB += vb.x * Wt1[(k + 0) * 64 + f] + vb.y * Wt1[(k + 1) * 64 + f]
                + vb.z * Wt1[(k + 2) * 64 + f] + vb.w * Wt1[(k + 3) * 64 + f];
        }
        P2[(size_t)row * 64 + f] = aA;
        Q2[(size_t)row * 64 + f] = aB;
    }
}

// ---------------- K3: layer-2 agg + score + colsum + treatment -----------------
__global__ void k3_agg_score(const int* __restrict__ cnt, const float2* __restrict__ pairs,
                             const float* __restrict__ P2, const float* __restrict__ Q2,
                             const float* __restrict__ bg1, const float* __restrict__ bt1,
                             const float* __restrict__ a,
                             const float* __restrict__ Wpp, const float* __restrict__ bpp,
                             const float* __restrict__ Wpp2, const float* __restrict__ bpp2,
                             float* __restrict__ rep_o, float* __restrict__ rep_t,
                             float* __restrict__ s_src, float* __restrict__ s_dst,
                             float* __restrict__ colsum, float* __restrict__ out_trt) {
    __shared__ float rts[8 * 64];
    int tid = threadIdx.x, row0 = blockIdx.x * 8, sub = tid >> 6, f = tid & 63;
    float bo = bg1[f], bt = bt1[f];
    float a0c = a[f], a1c = a[64 + f], a2c = a[128 + f], a3c = a[192 + f];
    #pragma unroll
    for (int g = 0; g < 2; ++g) {
        int lr = g * 4 + sub, row = row0 + lr;
        int c = min(cnt[row], CAP);
        float2 pr = make_float2(0.f, 0.f);
        if (f < c) pr = pairs[(size_t)row * CAP + f];
        int c_l = __float_as_int(pr.x); float v_l = pr.y;
        float a0 = 0.f, a1 = 0.f, b0 = 0.f, b1 = 0.f;
        for (int p = 0; p < c; p += 8) {
            #pragma unroll
            for (int j = 0; j < 8; j += 2) {
                float vv0 = __shfl(v_l, p + j, 64);     int cc0 = __shfl(c_l, p + j, 64);
                float vv1 = __shfl(v_l, p + j + 1, 64); int cc1 = __shfl(c_l, p + j + 1, 64);
                a0 += vv0 * P2[(size_t)cc0 * 64 + f];
                b0 += vv0 * Q2[(size_t)cc0 * 64 + f];
                a1 += vv1 * P2[(size_t)cc1 * 64 + f];
                b1 += vv1 * Q2[(size_t)cc1 * 64 + f];
            }
        }
        float vo = fmaxf(a0 + a1 + bo, 0.0f);
        float vt = fmaxf(b0 + b1 + bt, 0.0f);
        rep_o[(size_t)row * 64 + f] = vo;
        rep_t[(size_t)row * 64 + f] = vt;
        rts[lr * 64 + f] = vt;
        float ps = wave_sum(vo * a0c + vt * a1c);
        float pd = wave_sum(vo * a2c + vt * a3c);
        if (f == 0) { s_src[row] = ps; s_dst[row] = pd; }
    }
    __syncthreads();
    if (sub == 0) {                       // one block-reduced atomic per feature
        float cs = 0.0f;
        #pragma unroll
        for (int lr = 0; lr < 8; ++lr) cs += rts[lr * 64 + f];
        atomicAdd(&colsum[f], cs);
    }
    float bp = bpp[f], w20 = Wpp2[f * 2 + 0], w21 = Wpp2[f * 2 + 1];
    #pragma unroll
    for (int g = 0; g < 2; ++g) {
        int lr = g * 4 + sub, row = row0 + lr;
        const float* rr = rts + lr * 64;
        float u = bp;
        #pragma unroll 8
        for (int k = 0; k < 64; k += 4) {
            float4 rv = *(const float4*)(rr + k);
            u += rv.x * Wpp[(k + 0) * 64 + f] + rv.y * Wpp[(k + 1) * 64 + f]
               + rv.z * Wpp[(k + 2) * 64 + f] + rv.w * Wpp[(k + 3) * 64 + f];
        }
        float p0 = wave_sum(u * w20);
        float p1 = wave_sum(u * w21);
        if (f == 0) {
            out_trt[(size_t)row * 2 + 0] = 1.0f / (1.0f + expf(-(p0 + bpp2[0])));
            out_trt[(size_t)row * 2 + 1] = 1.0f / (1.0f + expf(-(p1 + bpp2[1])));
        }
    }
}

// ---------------- K4: attention + outcome heads + select ----------------------
__global__ void k4_attn_heads(const int* __restrict__ cnt, const float2* __restrict__ pairs,
                              const float* __restrict__ s_src, const float* __restrict__ s_dst,
                              const float* __restrict__ colsum,
                              const float* __restrict__ rep_o, const float* __restrict__ rep_t,
                              const float* __restrict__ W000, const float* __restrict__ b000,
                              const float* __restrict__ W001, const float* __restrict__ b001,
                              const float* __restrict__ W100, const float* __restrict__ b100,
                              const float* __restrict__ W101, const float* __restrict__ b101,
                              const float* __restrict__ Wo0, const float* __restrict__ bo0,
                              const float* __restrict__ Wo1, const float* __restrict__ bo1,
                              const int* __restrict__ t,
                              float* __restrict__ out_y, float* __restrict__ out_rep) {
    __shared__ float reps[8 * 64], u0s[8 * 64], u1s[8 * 64];
    int tid = threadIdx.x, row0 = blockIdx.x * 8, sub = tid >> 6, f = tid & 63;
    float csf = colsum[f];
    #pragma unroll
    for (int g = 0; g < 2; ++g) {
        int lr = g * 4 + sub, row = row0 + lr;
        int c = min(cnt[row], CAP);
        float ssrc = s_src[row];
        int   col_l = (f < c) ? __float_as_int(pairs[(size_t)row * CAP + f].x) : 0;
        float s_l   = (f < c) ? ssrc + s_dst[col_l] : -1e30f;
        float m = fmaxf(wave_max(s_l), 0.0f);     // zeros of the dense row join the max
        float e_l = (f < c) ? expf(s_l - m) : 0.0f;
        float em = expf(-m);
        float Z = wave_sum(e_l) + (float)(N_NODES - c) * em;
        float g_l = (f < c) ? (e_l - em) : 0.0f;  // lanes >= c contribute 0 in overshoot
        float a0 = 0.f, a1 = 0.f, a2 = 0.f, a3 = 0.f;
        for (int p = 0; p < c; p += 8) {
            #pragma unroll
            for (int j = 0; j < 8; j += 4) {
                float g0 = __shfl(g_l, p + j + 0, 64); int c0 = __shfl(col_l, p + j + 0, 64);
                float g1 = __shfl(g_l, p + j + 1, 64); int c1 = __shfl(col_l, p + j + 1, 64);
                float g2 = __shfl(g_l, p + j + 2, 64); int c2 = __shfl(col_l, p + j + 2, 64);
                float g3 = __shfl(g_l, p + j + 3, 64); int c3 = __shfl(col_l, p + j + 3, 64);
                a0 += g0 * rep_t[(size_t)c0 * 64 + f];
                a1 += g1 * rep_t[(size_t)c1 * 64 + f];
                a2 += g2 * rep_t[(size_t)c2 * 64 + f];
                a3 += g3 * rep_t[(size_t)c3 * 64 + f];
            }
        }
        float outv = ((a0 + a1 + a2 + a3) + em * csf) / Z + rep_o[(size_t)row * 64 + f];
        out_rep[(size_t)row * 64 + f] = outv;
        reps[lr * 64 + f] = outv;
    }
    __syncthreads();
    float bA = b000[f], bB = b100[f];
    #pragma unroll
    for (int g = 0; g < 2; ++g) {
        int lr = g * 4 + sub;
        const float* rr = reps + lr * 64;
        float u0 = bA, u1 = bB;
        #pragma unroll 8
        for (int k = 0; k < 64; k += 4) {
            float4 rv = *(const float4*)(rr + k);
            u0 += rv.x * W000[(k + 0) * 64 + f] + rv.y * W000[(k + 1) * 64 + f]
                + rv.z * W000[(k + 2) * 64 + f] + rv.w * W000[(k + 3) * 64 + f];
            u1 += rv.x * W100[(k + 0) * 64 + f] + rv.y * W100[(k + 1) * 64 + f]
                + rv.z * W100[(k + 2) * 64 + f] + rv.w * W100[(k + 3) * 64 + f];
        }
        u0s[lr * 64 + f] = fmaxf(u0, 0.0f);
        u1s[lr * 64 + f] = fmaxf(u1, 0.0f);
    }
    __syncthreads();
    float bC = b001[f], bD = b101[f], wo0 = Wo0[f], wo1 = Wo1[f];
    #pragma unroll
    for (int g = 0; g < 2; ++g) {
        int lr = g * 4 + sub, row = row0 + lr;
        const float* r0 = u0s + lr * 64;
        const float* r1 = u1s + lr * 64;
        float v0 = bC, v1 = bD;
        #pragma unroll 8
        for (int k = 0; k < 64; k += 4) {
            float4 q0 = *(const float4*)(r0 + k);
            float4 q1 = *(const float4*)(r1 + k);
            v0 += q0.x * W001[(k + 0) * 64 + f] + q0.y * W001[(k + 1) * 64 + f]
                + q0.z * W001[(k + 2) * 64 + f] + q0.w * W001[(k + 3) * 64 + f];
            v1 += q1.x * W101[(k + 0) * 64 + f] + q1.y * W101[(k + 1) * 64 + f]
                + q1.z * W101[(k + 2) * 64 + f] + q1.w * W101[(k + 3) * 64 + f];
        }
        float y0 = wave_sum(fmaxf(v0, 0.0f) * wo0);
        float y1 = wave_sum(fmaxf(v1, 0.0f) * wo1);
        if (f == 0)
            out_y[row] = (t[row] > 0) ? (y1 + bo1[0]) : (y0 + bo0[0]);
    }
}

// ---------------- launch ----------------

extern "C" void kernel_launch(void* const* d_in, const int* in_sizes, int n_in,
                              void* d_out, int out_size, void* d_ws, size_t ws_size,
                              hipStream_t stream) {
    const float* x    = (const float*)d_in[0];
    const float* adj  = (const float*)d_in[1];
    const int*   t    = (const int*)d_in[2];
    const float* Wg0  = (const float*)d_in[3];
    const float* bg0  = (const float*)d_in[4];
    const float* Wg1  = (const float*)d_in[5];
    const float* bg1  = (const float*)d_in[6];
    const float* Wt0  = (const float*)d_in[7];
    const float* bt0  = (const float*)d_in[8];
    const float* Wt1  = (const float*)d_in[9];
    const float* bt1  = (const float*)d_in[10];
    const float* W000 = (const float*)d_in[11];
    const float* b000 = (const float*)d_in[12];
    const float* W001 = (const float*)d_in[13];
    const float* b001 = (const float*)d_in[14];
    const float* W100 = (const float*)d_in[15];
    const float* b100 = (const float*)d_in[16];
    const float* W101 = (const float*)d_in[17];
    const float* b101 = (const float*)d_in[18];
    const float* Wo0  = (const float*)d_in[19];
    const float* bo0  = (const float*)d_in[20];
    const float* Wo1  = (const float*)d_in[21];
    const float* bo1  = (const float*)d_in[22];
    const float* Wpp  = (const float*)d_in[23];
    const float* bpp  = (const float*)d_in[24];
    const float* Wpp2 = (const float*)d_in[25];
    const float* bpp2 = (const float*)d_in[26];
    const float* a    = (const float*)d_in[27];

    float* ws = (float*)d_ws;
    int*    cnt    = (int*)(ws + OFF_CNT);
    float*  colsum = ws + OFF_COLSUM;
    float*  s_src  = ws + OFF_SSRC;
    float*  s_dst  = ws + OFF_SDST;
    float2* pairs  = (float2*)(ws + OFF_PAIRS);
    float*  B1     = ws + OFF_B1;   // x@Wg0 -> (K3) rep_o
    float*  B2     = ws + OFF_B2;   // x@Wt0 -> (K3) rep_t
    float*  B3     = ws + OFF_B3;   // layer2 pre-agg outcome
    float*  B4     = ws + OFF_B4;   // layer2 pre-agg treatment

    float* out_y   = (float*)d_out;                            // [N]
    float* out_rep = (float*)d_out + N_NODES;                  // [N,64]
    float* out_trt = (float*)d_out + N_NODES + N_NODES * 64;   // [N,2]

    k1_fused<<<TOTAL_K1, 256, 0, stream>>>((const fx4*)adj, x, Wg0, Wt0,
                                           cnt, pairs, colsum, B1, B2);
    k2_agg_gemm<<<1250, 256, 0, stream>>>(cnt, pairs, B1, B2, bg0, bt0, Wg1, Wt1, B3, B4);
    k3_agg_score<<<1250, 256, 0, stream>>>(cnt, pairs, B3, B4, bg1, bt1, a,
                                           Wpp, bpp, Wpp2, bpp2,
                                           B1, B2, s_src, s_dst, colsum, out_trt);
    k4_attn_heads<<<1250, 256, 0, stream>>>(cnt, pairs, s_src, s_dst, colsum, B1, B2,
                                            W000, b000, W001, b001,
                                            W100, b100, W101, b101,
                                            Wo0, bo0, Wo1, bo1, t, out_y, out_rep);
}